// Round 1
// baseline (130.617 us; speedup 1.0000x reference)
//
#include <hip/hip_runtime.h>

// Head row counts: B*H*W*3
constexpr int N13 = 32 * 13 * 13 * 3;   // 16224
constexpr int N26 = 32 * 26 * 26 * 3;   // 64896
constexpr int N52 = 32 * 52 * 52 * 3;   // 259584
constexpr int NTOT = N13 + N26 + N52;   // 340704

template <int H>
__device__ __forceinline__ void decode_head(const float* __restrict__ in,
                                            float* __restrict__ out,
                                            int r, float thresh,
                                            float aw0, float ah0,
                                            float aw1, float ah1,
                                            float aw2, float ah2) {
    constexpr int W = H;
    constexpr int PLANE = H * W;
    constexpr float t = 416.0f / (float)H;

    // row layout within a head: (((b*H + y)*W + x)*3 + a)
    const int a    = r % 3;
    const int cell = r / 3;
    const int x    = cell % W;
    const int rest = cell / W;
    const int y    = rest % H;
    const int b    = rest / H;

    // input layout: ((b*255 + a*85 + f)*H + y)*W + x, f in [0,5)
    const float* base = in + ((((size_t)b * 255 + (size_t)a * 85) * H + y) * W + x);

    const float conf = base[0];
    const float o1   = base[PLANE * 1];
    const float o2   = base[PLANE * 2];
    const float o3   = base[PLANE * 3];
    const float o4   = base[PLANE * 4];

    const bool m = conf > thresh;

    const float aw = (a == 0) ? aw0 : ((a == 1) ? aw1 : aw2);
    const float ah = (a == 0) ? ah0 : ((a == 1) ? ah1 : ah2);

    const float n  = m ? (float)b : 0.0f;
    const float cx = m ? ((float)x + o1) * t : 0.0f;
    const float cy = m ? ((float)y + o2) * t : 0.0f;
    const float w  = m ? aw * __expf(o3) : 0.0f;
    const float h  = m ? ah * __expf(o4) : 0.0f;

    float* o = out + (size_t)r * 5;
    o[0] = n;
    o[1] = cx;
    o[2] = cy;
    o[3] = w;
    o[4] = h;
}

__global__ __launch_bounds__(256) void yolo_decode_all(
    const float* __restrict__ in13,
    const float* __restrict__ in26,
    const float* __restrict__ in52,
    const float* __restrict__ thp,
    float* __restrict__ out) {
    const int r = blockIdx.x * 256 + threadIdx.x;
    const float thresh = *thp;
    if (r < N13) {
        decode_head<13>(in13, out, r, thresh,
                        116.0f, 90.0f, 156.0f, 198.0f, 373.0f, 326.0f);
    } else if (r < N13 + N26) {
        decode_head<26>(in26, out + (size_t)N13 * 5, r - N13, thresh,
                        30.0f, 61.0f, 62.0f, 45.0f, 59.0f, 119.0f);
    } else if (r < NTOT) {
        decode_head<52>(in52, out + (size_t)(N13 + N26) * 5, r - (N13 + N26), thresh,
                        10.0f, 13.0f, 16.0f, 30.0f, 33.0f, 23.0f);
    }
}

extern "C" void kernel_launch(void* const* d_in, const int* in_sizes, int n_in,
                              void* d_out, int out_size, void* d_ws, size_t ws_size,
                              hipStream_t stream) {
    const float* in13 = (const float*)d_in[0];
    const float* in26 = (const float*)d_in[1];
    const float* in52 = (const float*)d_in[2];
    const float* thp  = (const float*)d_in[3];
    float* out = (float*)d_out;

    const int blocks = (NTOT + 255) / 256;  // 1331
    yolo_decode_all<<<blocks, 256, 0, stream>>>(in13, in26, in52, thp, out);
}

// Round 2
// 130.000 us; speedup vs baseline: 1.0047x; 1.0047x over previous
//
#include <hip/hip_runtime.h>

// Heads: B=32 images, 3 anchors, 85 fields (we need first 5), H=W in {13,26,52}
constexpr int B_IMG = 32;
constexpr int N13 = B_IMG * 13 * 13 * 3;   // 16224 rows
constexpr int N26 = B_IMG * 26 * 26 * 3;   // 64896 rows

constexpr int CELLS_PER_BLK = 256;
constexpr int BLK13 = (B_IMG * 13 * 13 + CELLS_PER_BLK - 1) / CELLS_PER_BLK;  // 22
constexpr int BLK26 = (B_IMG * 26 * 26 + CELLS_PER_BLK - 1) / CELLS_PER_BLK;  // 85
constexpr int BLK52 = (B_IMG * 52 * 52 + CELLS_PER_BLK - 1) / CELLS_PER_BLK;  // 338
constexpr int NBLK  = BLK13 + BLK26 + BLK52;                                  // 445

template <int H>
__device__ __forceinline__ void decode_head_blk(
    const float* __restrict__ in,   // head input base
    float* __restrict__ outf,       // head output base (floats)
    int blk, int tid, float thresh,
    float aw0, float ah0, float aw1, float ah1, float aw2, float ah2) {
    constexpr int W = H;
    constexpr int PLANE = H * W;
    constexpr int NCELLS = B_IMG * PLANE;
    constexpr float t = 416.0f / (float)H;

    __shared__ float lds[CELLS_PER_BLK * 15];  // 15 KiB: 256 cells x 3 anchors x 5 floats

    const int cell0  = blk * CELLS_PER_BLK;
    const int nvalid = min(CELLS_PER_BLK, NCELLS - cell0);
    const int cell   = cell0 + tid;

    if (tid < nvalid) {
        // cell -> (img, y, x); x fastest => consecutive lanes read consecutive floats
        const int img = cell / PLANE;
        const int cip = cell - img * PLANE;
        const int y   = cip / W;
        const int x   = cip - y * W;
        const float fx = (float)x, fy = (float)y, fb = (float)img;

#pragma unroll
        for (int a = 0; a < 3; ++a) {
            const float* base = in + (size_t)(img * 255 + a * 85) * PLANE + cip;
            const float conf = base[0];
            const float o1   = base[PLANE * 1];
            const float o2   = base[PLANE * 2];
            const float o3   = base[PLANE * 3];
            const float o4   = base[PLANE * 4];

            const bool m = conf > thresh;
            const float aw = (a == 0) ? aw0 : ((a == 1) ? aw1 : aw2);
            const float ah = (a == 0) ? ah0 : ((a == 1) ? ah1 : ah2);

            // LDS layout mirrors output order: (cellLocal*3 + a)*5 + f
            // write stride 15 floats: coprime with 32 banks -> only free 2-way wave64 aliasing
            float* s = &lds[(tid * 3 + a) * 5];
            s[0] = m ? fb : 0.0f;
            s[1] = m ? (fx + o1) * t : 0.0f;
            s[2] = m ? (fy + o2) * t : 0.0f;
            s[3] = m ? aw * __expf(o3) : 0.0f;
            s[4] = m ? ah * __expf(o4) : 0.0f;
        }
    }
    __syncthreads();

    // Flush LDS -> global as contiguous float4 (nvalid*15 is divisible by 4 for all
    // tails at these sizes: 32*15=480, 128*15=1920, 256*15=3840)
    const int nvec = (nvalid * 15) >> 2;
    float4* ov = (float4*)(outf + (size_t)cell0 * 15);
    const float4* sv = (const float4*)lds;
    for (int i = tid; i < nvec; i += CELLS_PER_BLK) {
        ov[i] = sv[i];
    }
}

__global__ __launch_bounds__(256) void yolo_decode_all(
    const float* __restrict__ in13,
    const float* __restrict__ in26,
    const float* __restrict__ in52,
    const float* __restrict__ thp,
    float* __restrict__ out) {
    const int tid = threadIdx.x;
    const float thresh = *thp;
    const int blk = blockIdx.x;
    if (blk < BLK13) {
        decode_head_blk<13>(in13, out, blk, tid, thresh,
                            116.0f, 90.0f, 156.0f, 198.0f, 373.0f, 326.0f);
    } else if (blk < BLK13 + BLK26) {
        decode_head_blk<26>(in26, out + (size_t)N13 * 5, blk - BLK13, tid, thresh,
                            30.0f, 61.0f, 62.0f, 45.0f, 59.0f, 119.0f);
    } else {
        decode_head_blk<52>(in52, out + (size_t)(N13 + N26) * 5, blk - (BLK13 + BLK26), tid, thresh,
                            10.0f, 13.0f, 16.0f, 30.0f, 33.0f, 23.0f);
    }
}

extern "C" void kernel_launch(void* const* d_in, const int* in_sizes, int n_in,
                              void* d_out, int out_size, void* d_ws, size_t ws_size,
                              hipStream_t stream) {
    const float* in13 = (const float*)d_in[0];
    const float* in26 = (const float*)d_in[1];
    const float* in52 = (const float*)d_in[2];
    const float* thp  = (const float*)d_in[3];
    float* out = (float*)d_out;

    yolo_decode_all<<<NBLK, 256, 0, stream>>>(in13, in26, in52, thp, out);
}